// Round 10
// baseline (88.819 us; speedup 1.0000x reference)
//
#include <hip/hip_runtime.h>
#include <hip/hip_bf16.h>
#include <stdint.h>

// ---------------------------------------------------------------------------
// MultiScaleAttention: x[4,128,4096] -> 3x conv1x1+PReLU -> attention -> out
//   conv (fused transpose): Q [n][s][64] bf16 (*log2e), K/V in MFMA-fragment-
//   ready GLOBAL layouts (1KB contiguous per wave-fragment -> linear LDS
//   staging, zero bank conflicts). Split-bf16 MFMA for fp32-level accuracy.
//   attn: q=64/wave (q=256/block), KVBLK=32, 3-buffer LDS, counted-vmcnt
//   pipeline (T4): raw s_barrier + s_waitcnt vmcnt(3) -- staging loads stay
//   in flight across barriers; vmcnt(0) only on the last tile.
//   p = exp2(S^T) unnormalized; num bf16 + den f32 partials over 8 kv-splits.
// KF layout: [n][t(32k)][d0(4)][slot(64)]*16B, slot=hi*32+l31 ->
//            K[t*32+l31][d0*16+hi*8 ..+8]
// VF layout: [n][t(32k)][dvb*2+kc(8)][slot(64)]*16B, slot=hi*32+l31 ->
//            V^T[dvb*32+l31][t*32+kc*16+hi*8 ..+8]
// ---------------------------------------------------------------------------

typedef float   f32x16 __attribute__((ext_vector_type(16)));
typedef __bf16  bf16x8 __attribute__((ext_vector_type(8)));
typedef __bf16  bf16x2 __attribute__((ext_vector_type(2)));
typedef unsigned int u32x4 __attribute__((ext_vector_type(4)));
typedef unsigned int u32x2 __attribute__((ext_vector_type(2)));

#define L2E 1.4426950408889634f

// workspace layout (bytes); ws_size ~268MB
#define Q_OFF   (0u)                          // [4][4096][64] bf16 = 2MB
#define KF_OFF  (2u << 20)                    // frag-K, 512KB/batch = 2MB
#define VF_OFF  (4u << 20)                    // frag-V, 1MB/batch = 4MB
#define DEN_OFF (8u << 20)                    // [4][16][8][256] f32 = 512KB
#define WH_OFF  ((8u << 20) + (1u << 19))     // W hi bf16 [256][128] = 64KB
#define WL_OFF  (WH_OFF + (1u << 16))
#define OP_OFF  (9u << 20)                    // num bf16 [4][16][8][128][256] = 33.5MB

__device__ inline unsigned short f2bf(float f) {
  unsigned u = __builtin_bit_cast(unsigned, f);
  return (unsigned short)((u + 0x7FFFu + ((u >> 16) & 1u)) >> 16);  // RNE
}
__device__ inline float bf2f(unsigned short h) {
  unsigned u = ((unsigned)h) << 16;
  return __builtin_bit_cast(float, u);
}
__device__ inline unsigned pack2(float a, float b) {   // v_cvt_pk_bf16_f32
  bf16x2 t = { (__bf16)a, (__bf16)b };
  return __builtin_bit_cast(unsigned, t);
}

__device__ inline void gld_lds16(const void* g, void* l) {
  __builtin_amdgcn_global_load_lds(
      (const __attribute__((address_space(1))) unsigned*)g,
      (__attribute__((address_space(3))) unsigned*)l, 16, 0, 0);
}

// --------------------------- kernel 0: cast weights ------------------------
__global__ void wcast_kernel(const float* __restrict__ w1, const float* __restrict__ w2,
                             const float* __restrict__ wa, char* __restrict__ ws) {
  int idx = blockIdx.x * 256 + threadIdx.x;   // 32 blocks
  unsigned short* WH = (unsigned short*)(ws + WH_OFF);
  unsigned short* WL = (unsigned short*)(ws + WL_OFF);
#pragma unroll
  for (int r = 0; r < 4; ++r) {
    int i = r * 8192 + idx;                   // 0..32767
    int oc = i >> 7, c = i & 127;
    float v = oc < 64 ? w1[oc * 128 + c]
            : (oc < 128 ? w2[(oc - 64) * 128 + c] : wa[(oc - 128) * 128 + c]);
    unsigned short h = f2bf(v);
    WH[i] = h;
    WL[i] = f2bf(v - bf2f(h));
  }
}

// ------- kernel 1: conv1x1 + bias + PReLU -> Q, KF, VF (fused transpose) ----
// 512 blocks = 4n * 128 s-tiles(32). Waves: 0->Q(*L2E), 1->K, 2,3->V.
__global__ __launch_bounds__(256) void conv_kernel(
    const float* __restrict__ x, char* __restrict__ ws,
    const float* __restrict__ b1, const float* __restrict__ a1,
    const float* __restrict__ b2, const float* __restrict__ a2,
    const float* __restrict__ ba, const float* __restrict__ aa) {
  int bid = blockIdx.x;
  int n = bid >> 7, st = bid & 127;           // st == kv tile index t
  int sb = st * 32;
  int tid = threadIdx.x;
  int wid = tid >> 6, lane = tid & 63, l31 = lane & 31, hi = lane >> 5;

  __shared__ float xl[128][36];         // x-tile transpose; later reused as vl
  __shared__ float tl[2][64][33];       // Q/K f32 transpose buffers
  float* vl = (float*)xl;               // [128][33] V f32, reuse after MFMA

  const float* xb = x + (size_t)n * 128 * 4096;
#pragma unroll
  for (int it = 0; it < 4; ++it) {      // load 128x32 f32 tile
    int flat4 = tid + 256 * it;
    int c = flat4 >> 3, s4 = flat4 & 7;
    float4 v = *(const float4*)(xb + (size_t)c * 4096 + sb + s4 * 4);
    *(float4*)&xl[c][s4 * 4] = v;
  }
  __syncthreads();

  const char* WH = ws + WH_OFF;
  const char* WL = ws + WL_OFF;
  int oc0 = wid * 64;

  f32x16 acc[2];
  acc[0] = 0.f; acc[1] = 0.f;
#pragma unroll
  for (int c0 = 0; c0 < 8; ++c0) {
    __bf16 eh[8], el[8];
#pragma unroll
    for (int j = 0; j < 8; ++j) {
      float v = xl[c0 * 16 + hi * 8 + j][l31];
      __bf16 h = (__bf16)v;
      eh[j] = h;
      el[j] = (__bf16)(v - (float)h);
    }
    bf16x8 xh = {eh[0], eh[1], eh[2], eh[3], eh[4], eh[5], eh[6], eh[7]};
    bf16x8 xlo = {el[0], el[1], el[2], el[3], el[4], el[5], el[6], el[7]};
#pragma unroll
    for (int mb = 0; mb < 2; ++mb) {
      size_t wo = (size_t)(oc0 + mb * 32 + l31) * 256 + c0 * 32 + hi * 16;
      bf16x8 wh = *(const bf16x8*)(WH + wo);
      bf16x8 wl = *(const bf16x8*)(WL + wo);
      acc[mb] = __builtin_amdgcn_mfma_f32_32x32x16_bf16(wh, xh, acc[mb], 0, 0, 0);
      acc[mb] = __builtin_amdgcn_mfma_f32_32x32x16_bf16(wh, xlo, acc[mb], 0, 0, 0);
      acc[mb] = __builtin_amdgcn_mfma_f32_32x32x16_bf16(wl, xh, acc[mb], 0, 0, 0);
    }
  }
  __syncthreads();                      // all waves done reading xl

  if (wid < 2) {
    const float* bb = wid ? b2 : b1;
    float slope = wid ? a2[0] : a1[0];
    float scl = wid ? 1.0f : L2E;       // fold softmax log2e into Q
#pragma unroll
    for (int mb = 0; mb < 2; ++mb)
#pragma unroll
      for (int reg = 0; reg < 16; ++reg) {
        int row = mb * 32 + (reg & 3) + 8 * (reg >> 2) + 4 * hi;
        float y = acc[mb][reg] + bb[row];
        y = fmaxf(y, 0.f) + slope * fminf(y, 0.f);
        tl[wid][row][l31] = y * scl;
      }
  } else {
    float slope = aa[0];
#pragma unroll
    for (int mb = 0; mb < 2; ++mb)
#pragma unroll
      for (int reg = 0; reg < 16; ++reg) {
        int dv = (wid - 2) * 64 + mb * 32 + (reg & 3) + 8 * (reg >> 2) + 4 * hi;
        float y = acc[mb][reg] + ba[dv];
        y = fmaxf(y, 0.f) + slope * fminf(y, 0.f);
        vl[dv * 33 + l31] = y;
      }
  }
  __syncthreads();

  if (wid == 0) {                       // Q natural [s][64] bf16
    char* Qg = ws + Q_OFF + (size_t)n * (4096 * 128);
#pragma unroll
    for (int it = 0; it < 4; ++it) {
      int sl = (lane >> 3) + it * 8;
      u32x4 pv;
#pragma unroll
      for (int p = 0; p < 4; ++p)
        pv[p] = pack2(tl[0][(lane & 7) * 8 + 2 * p][sl],
                      tl[0][(lane & 7) * 8 + 2 * p + 1][sl]);
      *(u32x4*)(Qg + (size_t)(sb + sl) * 128 + (lane & 7) * 16) = pv;
    }
  } else if (wid == 1) {                // K fragment layout
    char* KFb = ws + KF_OFF + (size_t)n * (512 << 10);
    int d0 = (lane & 7) >> 1, hs = lane & 1;
#pragma unroll
    for (int it = 0; it < 4; ++it) {
      int sl = (lane >> 3) + it * 8;
      u32x4 pv;
#pragma unroll
      for (int p = 0; p < 4; ++p)
        pv[p] = pack2(tl[1][(lane & 7) * 8 + 2 * p][sl],
                      tl[1][(lane & 7) * 8 + 2 * p + 1][sl]);
      *(u32x4*)(KFb + ((size_t)(st * 4 + d0) * 64 + hs * 32 + sl) * 16) = pv;
    }
  }
  // all 256 threads: V fragment stores (512 units of 16B)
  {
    char* VFb = ws + VF_OFF + (size_t)n * (1u << 20);
#pragma unroll
    for (int r = 0; r < 2; ++r) {
      int u = tid + r * 256;
      int dv = u >> 2, sc = u & 3;
      u32x4 pv;
#pragma unroll
      for (int p = 0; p < 4; ++p)
        pv[p] = pack2(vl[dv * 33 + sc * 8 + 2 * p], vl[dv * 33 + sc * 8 + 2 * p + 1]);
      int unit = st * 8 + (dv >> 5) * 2 + (sc >> 1);
      *(u32x4*)(VFb + ((size_t)unit * 64 + (sc & 1) * 32 + (dv & 31)) * 16) = pv;
    }
  }
}

// --------------------------- kernel 2: flash attention ----------------------
// 512 blocks: bid = ((batch*16+qt)<<3)|split -> split==XCD (bid%8).
// Block = 4 waves * 64 q = 256 q; kv = split*512..+512 (16 tiles of 32).
// 3-buffer LDS (36KB); counted-vmcnt pipeline: per region
//   {vmcnt(3); s_barrier; stage(t+2); QK(t)+SM(t)+PV(t); s_barrier}
// -> staging loads for t+1/t+2 stay in flight across barriers (no drain).
__global__ __launch_bounds__(256, 2) void attn_kernel(char* __restrict__ ws) {
  int bid = blockIdx.x;
  int split = bid & 7;
  int qt = (bid >> 3) & 15;
  int batch = bid >> 7;
  int tid = threadIdx.x;
  int wid = tid >> 6, lane = tid & 63, l31 = lane & 31, hi = lane >> 5;

  const char* Qb  = ws + Q_OFF  + (size_t)batch * (4096 * 128);
  const char* Kt0 = ws + KF_OFF + (size_t)batch * (512 << 10) +
                    (size_t)(split * 16) * 4096;
  const char* Vt0 = ws + VF_OFF + (size_t)batch * (1u << 20) +
                    (size_t)(split * 16) * 8192;

  __shared__ char sbuf[3][12288];       // [0,4K)=K tile, [4K,12K)=V tile

  int q0 = qt * 256 + wid * 64;
  int lo16 = lane * 16;

  bf16x8 qf0[4], qf1[4];                // Q frags for the wave's 2 q-sets
#pragma unroll
  for (int d0 = 0; d0 < 4; ++d0) {
    qf0[d0] = *(const bf16x8*)(Qb + (size_t)(q0 + l31) * 128 + d0 * 32 + hi * 16);
    qf1[d0] = *(const bf16x8*)(Qb + (size_t)(q0 + 32 + l31) * 128 + d0 * 32 + hi * 16);
  }

  f32x16 oacc[2][4];
#pragma unroll
  for (int qs = 0; qs < 2; ++qs)
#pragma unroll
    for (int i = 0; i < 4; ++i) oacc[qs][i] = 0.f;
  float denA0 = 0.f, denA1 = 0.f, denB0 = 0.f, denB1 = 0.f;

  // each wave stages 3 of the 12 1KB chunks (K: c<4, V: c>=4)
  auto stage = [&](int b, int t) {
#pragma unroll
    for (int i = 0; i < 3; ++i) {
      int c = wid * 3 + i;
      const char* src = (c < 4) ? Kt0 + (size_t)t * 4096 + c * 1024 + lo16
                                : Vt0 + (size_t)t * 8192 + (c - 4) * 1024 + lo16;
      gld_lds16(src, &sbuf[b][c * 1024]);
    }
  };

  stage(0, 0);                          // 3 outstanding
  stage(1, 1);                          // 6 outstanding

#pragma unroll
  for (int t = 0; t < 16; ++t) {
    // wait ONLY for tile t's 3 loads (this wave); t+1's stay in flight
    if (t < 15) asm volatile("s_waitcnt vmcnt(3)" ::: "memory");
    else        asm volatile("s_waitcnt vmcnt(0)" ::: "memory");
    __builtin_amdgcn_s_barrier();       // raw: no drain
    __builtin_amdgcn_sched_barrier(0);

    if (t + 2 < 16) stage((t + 2) % 3, t + 2);   // issue-early, overlaps compute

    const char* kb = sbuf[t % 3];
    const char* vb = kb + 4096;

    // QK both q-sets: S^T[k][q], k = (reg&3)+8*(reg>>2)+4*hi, q = l31
    f32x16 s0, s1;
    s0 = 0.f; s1 = 0.f;
    __builtin_amdgcn_s_setprio(1);
#pragma unroll
    for (int d0 = 0; d0 < 4; ++d0) {
      bf16x8 kf = *(const bf16x8*)(kb + d0 * 1024 + lo16);
      s0 = __builtin_amdgcn_mfma_f32_32x32x16_bf16(kf, qf0[d0], s0, 0, 0, 0);
      s1 = __builtin_amdgcn_mfma_f32_32x32x16_bf16(kf, qf1[d0], s1, 0, 0, 0);
    }
    __builtin_amdgcn_s_setprio(0);

    // softmax: p = exp2(s) (Q pre-scaled by log2e), unnormalized
    unsigned pk0[8], pk1[8];
#pragma unroll
    for (int m = 0; m < 8; ++m) {
      float a0 = __builtin_amdgcn_exp2f(s0[2 * m]);
      float a1 = __builtin_amdgcn_exp2f(s0[2 * m + 1]);
      if (m & 1) denA1 += a0 + a1; else denA0 += a0 + a1;
      pk0[m] = pack2(a0, a1);
      float b0 = __builtin_amdgcn_exp2f(s1[2 * m]);
      float b1 = __builtin_amdgcn_exp2f(s1[2 * m + 1]);
      if (m & 1) denB1 += b0 + b1; else denB0 += b0 + b1;
      pk1[m] = pack2(b0, b1);
    }

    // PV: O^T[dv][q] += V^T · P^T ; each vf read feeds both q-sets
#pragma unroll
    for (int kc = 0; kc < 2; ++kc) {
      const int bs = kc * 4;
      u32x2 r0 = __builtin_amdgcn_permlane32_swap(pk0[bs + 0], pk0[bs + 2],
                                                  false, false);
      u32x2 r1 = __builtin_amdgcn_permlane32_swap(pk0[bs + 1], pk0[bs + 3],
                                                  false, false);
      u32x4 pu0 = {r0.x, r1.x, r0.y, r1.y};
      bf16x8 pf0 = __builtin_bit_cast(bf16x8, pu0);
      u32x2 r2 = __builtin_amdgcn_permlane32_swap(pk1[bs + 0], pk1[bs + 2],
                                                  false, false);
      u32x2 r3 = __builtin_amdgcn_permlane32_swap(pk1[bs + 1], pk1[bs + 3],
                                                  false, false);
      u32x4 pu1 = {r2.x, r3.x, r2.y, r3.y};
      bf16x8 pf1 = __builtin_bit_cast(bf16x8, pu1);
      __builtin_amdgcn_s_setprio(1);
#pragma unroll
      for (int dvb = 0; dvb < 4; ++dvb) {
        bf16x8 vf = *(const bf16x8*)(vb + (dvb * 2 + kc) * 1024 + lo16);
        oacc[0][dvb] = __builtin_amdgcn_mfma_f32_32x32x16_bf16(vf, pf0,
                                                               oacc[0][dvb], 0, 0, 0);
        oacc[1][dvb] = __builtin_amdgcn_mfma_f32_32x32x16_bf16(vf, pf1,
                                                               oacc[1][dvb], 0, 0, 0);
      }
      __builtin_amdgcn_s_setprio(0);
    }

    __builtin_amdgcn_sched_barrier(0);
    __builtin_amdgcn_s_barrier();       // raw: reads of buf[t%3] done
  }

  // write numerator partials (bf16, cacheable -> L2/L3 for combine) + den
  unsigned short* OPu = (unsigned short*)(ws + OP_OFF) +
                        (size_t)((batch * 16 + qt) * 8 + split) * 32768;
#pragma unroll
  for (int qs = 0; qs < 2; ++qs) {
    int qloc = wid * 64 + qs * 32 + l31;
#pragma unroll
    for (int dvb = 0; dvb < 4; ++dvb)
#pragma unroll
      for (int reg = 0; reg < 16; ++reg) {
        int dv = dvb * 32 + (reg & 3) + 8 * (reg >> 2) + 4 * hi;
        OPu[dv * 256 + qloc] = f2bf(oacc[qs][dvb][reg]);
      }
    float den = qs ? (denB0 + denB1) : (denA0 + denA1);
    float dtot = den + __shfl_xor(den, 32, 64);
    if (hi == 0) {
      float* DEN = (float*)(ws + DEN_OFF) +
                   (size_t)((batch * 16 + qt) * 8 + split) * 256;
      DEN[qloc] = dtot;
    }
  }
}

// --------------------------- kernel 3: combine splits -----------------------
// 1024 blocks; each thread produces 8 consecutive outputs (vectorized loads).
__global__ __launch_bounds__(256) void combine_kernel(const char* __restrict__ ws,
                                                      float* __restrict__ out) {
  int idx8 = (blockIdx.x * 256 + threadIdx.x) * 8;  // 2^21 outputs [n][c][s]
  int n = idx8 >> 19;
  int dv = (idx8 >> 12) & 127;
  int s0 = idx8 & 4095;                 // 8-aligned
  int qt = s0 >> 8, ql = s0 & 255;
  const unsigned short* OPu = (const unsigned short*)(ws + OP_OFF);
  const float* DEN = (const float*)(ws + DEN_OFF);
  size_t pb = (size_t)((n * 16 + qt) * 8);
  float num[8], den[8];
#pragma unroll
  for (int j = 0; j < 8; ++j) { num[j] = 0.f; den[j] = 0.f; }
#pragma unroll
  for (int h = 0; h < 8; ++h) {
    bf16x8 v = *(const bf16x8*)(OPu + (pb + h) * 32768 + (size_t)dv * 256 + ql);
    const float* dp = DEN + (pb + h) * 256 + ql;
    float4 d0 = *(const float4*)dp;
    float4 d1 = *(const float4*)(dp + 4);
#pragma unroll
    for (int j = 0; j < 8; ++j) num[j] += (float)v[j];
    den[0] += d0.x; den[1] += d0.y; den[2] += d0.z; den[3] += d0.w;
    den[4] += d1.x; den[5] += d1.y; den[6] += d1.z; den[7] += d1.w;
  }
  float4 o0 = {num[0] / den[0], num[1] / den[1], num[2] / den[2], num[3] / den[3]};
  float4 o1 = {num[4] / den[4], num[5] / den[5], num[6] / den[6], num[7] / den[7]};
  *(float4*)&out[idx8] = o0;
  *(float4*)&out[idx8 + 4] = o1;
}

// ---------------------------------------------------------------------------
extern "C" void kernel_launch(void* const* d_in, const int* in_sizes, int n_in,
                              void* d_out, int out_size, void* d_ws, size_t ws_size,
                              hipStream_t stream) {
  (void)in_sizes; (void)n_in; (void)out_size; (void)ws_size;
  const float* x  = (const float*)d_in[0];
  const float* w1 = (const float*)d_in[1];
  const float* b1 = (const float*)d_in[2];
  const float* a1 = (const float*)d_in[3];
  const float* w2 = (const float*)d_in[4];
  const float* b2 = (const float*)d_in[5];
  const float* a2 = (const float*)d_in[6];
  const float* wa = (const float*)d_in[7];
  const float* ba = (const float*)d_in[8];
  const float* aa = (const float*)d_in[9];
  char* ws = (char*)d_ws;
  float* out = (float*)d_out;

  wcast_kernel<<<dim3(32), dim3(256), 0, stream>>>(w1, w2, wa, ws);
  conv_kernel<<<dim3(512), dim3(256), 0, stream>>>(x, ws, b1, a1, b2, a2, ba, aa);
  attn_kernel<<<dim3(512), dim3(256), 0, stream>>>(ws);
  combine_kernel<<<dim3(1024), dim3(256), 0, stream>>>(ws, out);
}

// Round 11
// 66.884 us; speedup vs baseline: 1.3280x; 1.3280x over previous
//
#include <hip/hip_runtime.h>
#include <hip/hip_bf16.h>
#include <stdint.h>

// ---------------------------------------------------------------------------
// MultiScaleAttention: x[4,128,4096] -> 3x conv1x1+PReLU -> attention -> out
//   conv (fused transpose): Q = e1^T * log2e [n][s][64], K = e2^T [n][s][64],
//   V^T = asm [n][128][4096] (bf16). Split-bf16 (hi+lo) MFMA ~ fp32 accuracy;
//   x converted to bf16 hi/lo AT LOAD into transposed LDS -> frag = 1 ds_read.
//   attn (R5-proven): KVBLK=32, 24KB LDS, 4 blocks/CU, grid 1024, q=32/wave;
//   S^T = K Q^T (swapped mfma), p = exp2(S^T) unnormalized,
//   O^T[dv][q] = V^T P^T; num bf16 + den f32 partials over 8 kv-splits.
//   combine: vectorized bf16x8/float4, 8 outputs/thread.
// ---------------------------------------------------------------------------

typedef float   f32x16 __attribute__((ext_vector_type(16)));
typedef __bf16  bf16x8 __attribute__((ext_vector_type(8)));
typedef __bf16  bf16x2 __attribute__((ext_vector_type(2)));
typedef unsigned int u32x4 __attribute__((ext_vector_type(4)));
typedef unsigned int u32x2 __attribute__((ext_vector_type(2)));

#define L2E 1.4426950408889634f

// workspace layout (bytes); ws_size ~268MB
#define Q_OFF   (0u)                          // [4][4096][64] bf16 = 2MB
#define K_OFF   (2u << 20)                    // [4][4096][64] bf16 = 2MB
#define V_OFF   (4u << 20)                    // [4][128][4096] bf16 = 4MB
#define DEN_OFF (8u << 20)                    // [4][32][8][128] f32 = 512KB
#define WH_OFF  ((8u << 20) + (1u << 19))     // W hi bf16 [256][128] = 64KB
#define WL_OFF  (WH_OFF + (1u << 16))
#define OP_OFF  (9u << 20)                    // num bf16 [4][32][8][128][128] = 33.5MB

__device__ inline unsigned short f2bf(float f) {   // hw v_cvt (RNE)
  __bf16 h = (__bf16)f;
  return __builtin_bit_cast(unsigned short, h);
}
__device__ inline float bf2f(unsigned short h) {
  unsigned u = ((unsigned)h) << 16;
  return __builtin_bit_cast(float, u);
}
__device__ inline unsigned pack2(float a, float b) {   // v_cvt_pk_bf16_f32
  bf16x2 t = { (__bf16)a, (__bf16)b };
  return __builtin_bit_cast(unsigned, t);
}

__device__ inline void gld_lds16(const void* g, void* l) {
  __builtin_amdgcn_global_load_lds(
      (const __attribute__((address_space(1))) unsigned*)g,
      (__attribute__((address_space(3))) unsigned*)l, 16, 0, 0);
}

// --------------------------- kernel 0: cast weights ------------------------
__global__ void wcast_kernel(const float* __restrict__ w1, const float* __restrict__ w2,
                             const float* __restrict__ wa, char* __restrict__ ws) {
  int idx = blockIdx.x * 256 + threadIdx.x;   // 32 blocks
  unsigned short* WH = (unsigned short*)(ws + WH_OFF);
  unsigned short* WL = (unsigned short*)(ws + WL_OFF);
#pragma unroll
  for (int r = 0; r < 4; ++r) {
    int i = r * 8192 + idx;                   // 0..32767
    int oc = i >> 7, c = i & 127;
    float v = oc < 64 ? w1[oc * 128 + c]
            : (oc < 128 ? w2[(oc - 64) * 128 + c] : wa[(oc - 128) * 128 + c]);
    __bf16 h = (__bf16)v;
    WH[i] = __builtin_bit_cast(unsigned short, h);
    WL[i] = f2bf(v - (float)h);
  }
}

// ------- kernel 1: conv1x1 + bias + PReLU -> Q,K,V (fused x transpose) ------
// 512 blocks = 4n * 128 s-tiles(32). Waves: 0->Q(*L2E), 1->K, 2,3->V.
// x converted to bf16 hi/lo at load into transposed LDS [32 s][152 c] bf16
// (304B row stride: even 4-per-bank b128 reads). Frag read = 1 ds_read_b128.
__global__ __launch_bounds__(256) void conv_kernel(
    const float* __restrict__ x, char* __restrict__ ws,
    const float* __restrict__ b1, const float* __restrict__ a1,
    const float* __restrict__ b2, const float* __restrict__ a2,
    const float* __restrict__ ba, const float* __restrict__ aa) {
  int bid = blockIdx.x;
  int n = bid >> 7, st = bid & 127;
  int sb = st * 32;
  int tid = threadIdx.x;
  int wid = tid >> 6, lane = tid & 63, l31 = lane & 31, hi = lane >> 5;

  __shared__ __bf16 xh[32][152];        // x^T hi, 304B rows
  __shared__ __bf16 xlo[32][152];       // x^T lo
  __shared__ float tl[2][64][33];       // Q/K f32 transpose buffers

  const float* xb = x + (size_t)n * 128 * 4096;
#pragma unroll
  for (int it = 0; it < 4; ++it) {      // load 128x32 f32 tile, cvt+transpose
    int flat4 = tid + 256 * it;
    int c = flat4 >> 3, s4 = flat4 & 7;
    float4 v = *(const float4*)(xb + (size_t)c * 4096 + sb + s4 * 4);
    float vv[4] = {v.x, v.y, v.z, v.w};
#pragma unroll
    for (int e = 0; e < 4; ++e) {
      int s = s4 * 4 + e;
      __bf16 h = (__bf16)vv[e];
      xh[s][c] = h;
      xlo[s][c] = (__bf16)(vv[e] - (float)h);
    }
  }
  __syncthreads();

  const char* WH = ws + WH_OFF;
  const char* WL = ws + WL_OFF;
  const char* xhB = (const char*)&xh[0][0];
  const char* xlB = (const char*)&xlo[0][0];
  int oc0 = wid * 64;

  f32x16 acc[2];
  acc[0] = 0.f; acc[1] = 0.f;
#pragma unroll
  for (int c0 = 0; c0 < 8; ++c0) {
    // B-frag: x^T[s=l31][k = c0*16 + hi*8 + j] -- one ds_read_b128 each
    int xo = l31 * 304 + c0 * 32 + hi * 16;
    bf16x8 xfh = *(const bf16x8*)(xhB + xo);
    bf16x8 xfl = *(const bf16x8*)(xlB + xo);
#pragma unroll
    for (int mb = 0; mb < 2; ++mb) {
      size_t wo = (size_t)(oc0 + mb * 32 + l31) * 256 + c0 * 32 + hi * 16;
      bf16x8 wh = *(const bf16x8*)(WH + wo);
      bf16x8 wl = *(const bf16x8*)(WL + wo);
      acc[mb] = __builtin_amdgcn_mfma_f32_32x32x16_bf16(wh, xfh, acc[mb], 0, 0, 0);
      acc[mb] = __builtin_amdgcn_mfma_f32_32x32x16_bf16(wh, xfl, acc[mb], 0, 0, 0);
      acc[mb] = __builtin_amdgcn_mfma_f32_32x32x16_bf16(wl, xfh, acc[mb], 0, 0, 0);
    }
  }

  char* Qw = ws + Q_OFF + (size_t)n * (4096 * 64 * 2);
  char* Kw = ws + K_OFF + (size_t)n * (4096 * 64 * 2);
  unsigned short* Vw = (unsigned short*)(ws + V_OFF) + (size_t)n * 128 * 4096;

  if (wid < 2) {
    const float* bb = wid ? b2 : b1;
    float slope = wid ? a2[0] : a1[0];
    float scl = wid ? 1.0f : L2E;       // fold softmax log2e into Q
#pragma unroll
    for (int mb = 0; mb < 2; ++mb)
#pragma unroll
      for (int reg = 0; reg < 16; ++reg) {
        int row = mb * 32 + (reg & 3) + 8 * (reg >> 2) + 4 * hi;
        float y = acc[mb][reg] + bb[row];
        y = fmaxf(y, 0.f) + slope * fminf(y, 0.f);
        tl[wid][row][l31] = y * scl;
      }
  } else {
    float slope = aa[0];
#pragma unroll
    for (int mb = 0; mb < 2; ++mb)
#pragma unroll
      for (int reg = 0; reg < 16; ++reg) {
        int dv = (wid - 2) * 64 + mb * 32 + (reg & 3) + 8 * (reg >> 2) + 4 * hi;
        float y = acc[mb][reg] + ba[dv];
        y = fmaxf(y, 0.f) + slope * fminf(y, 0.f);
        Vw[(size_t)dv * 4096 + sb + l31] = f2bf(y);
      }
  }
  __syncthreads();
  if (wid < 2) {   // LDS-transposed, coalesced bf16 store of Q/K [s][64]
    char* Og = wid ? Kw : Qw;
#pragma unroll
    for (int it = 0; it < 4; ++it) {
      int sl = (lane >> 3) + it * 8;
      u32x4 pv;
#pragma unroll
      for (int p = 0; p < 4; ++p)
        pv[p] = pack2(tl[wid][(lane & 7) * 8 + 2 * p][sl],
                      tl[wid][(lane & 7) * 8 + 2 * p + 1][sl]);
      *(u32x4*)(Og + (size_t)(sb + sl) * 128 + (lane & 7) * 16) = pv;
    }
  }
}

// --------------------------- kernel 2: flash attention ----------------------
// 1024 blocks: bid = ((batch*32+qt)<<3)|split -> split==XCD (bid%8).
// Block = 4 waves * 32 q = 128 q; kv range = split*512..+512 (16 tiles of 32).
// LDS 24KB, 4 blocks/CU -> 4 independent waves/SIMD.  [R5-proven structure]
__global__ __launch_bounds__(256, 4) void attn_kernel(char* __restrict__ ws) {
  int bid = blockIdx.x;
  int split = bid & 7;
  int qt = (bid >> 3) & 31;
  int batch = bid >> 8;
  int tid = threadIdx.x;
  int wid = tid >> 6, lane = tid & 63, l31 = lane & 31, hi = lane >> 5;

  const char* Qb = ws + Q_OFF + (size_t)batch * (4096 * 64 * 2);
  const char* Kb = ws + K_OFF + (size_t)batch * (4096 * 64 * 2);
  const char* Vb = ws + V_OFF + (size_t)batch * (128 * 4096 * 2);

  __shared__ char kbuf[2][32 * 128];    // [k][64d] bf16, XOR-swz slots (4KB ea)
  __shared__ char vbuf[2][128 * 64];    // [dv][32k] bf16, XOR-swz slots (8KB ea)

  int q0 = qt * 128 + wid * 32;

  bf16x8 qf[4];                         // Q B-frags: Q[q0+l31][16*d0 + 8*hi + j]
#pragma unroll
  for (int d0 = 0; d0 < 4; ++d0)
    qf[d0] = *(const bf16x8*)(Qb + (size_t)(q0 + l31) * 128 + d0 * 32 + hi * 16);

  f32x16 oacc[4];
#pragma unroll
  for (int i = 0; i < 4; ++i) oacc[i] = 0.f;
  float den = 0.f;

  int t0 = split * 16;                  // absolute 32-kv tile index base

  auto stage = [&](int b, int tile) {
    int kv0 = tile * 32;
    {                                   // K: 4KB, 1 instr/wave
      int base = wid * 1024;
      int L = base + (lane << 4);
      int r = L >> 7, sl = (L >> 4) & 7;
      const char* src = Kb + (size_t)(kv0 + r) * 128 + ((sl ^ (r & 7)) << 4);
      gld_lds16(src, &kbuf[b][base]);
    }
#pragma unroll
    for (int i = 0; i < 2; ++i) {       // V: 8KB, 2 instr/wave
      int base = wid * 2048 + i * 1024;
      int L = base + (lane << 4);
      int r = L >> 6, sl = (L >> 4) & 3;
      const char* src = Vb + (size_t)r * 8192 + kv0 * 2 + ((sl ^ (r & 3)) << 4);
      gld_lds16(src, &vbuf[b][base]);
    }
  };

  stage(0, t0);
  __syncthreads();
  int cur = 0;

  for (int t = 0; t < 16; ++t) {
    if (t + 1 < 16) stage(cur ^ 1, t0 + t + 1);

    // S^T[k][q] = K·Q^T  (q = l31; k = (reg&3)+8*(reg>>2)+4*hi)
    f32x16 sacc;
    sacc = 0.f;
    __builtin_amdgcn_s_setprio(1);
#pragma unroll
    for (int d0 = 0; d0 < 4; ++d0) {
      int r = l31;
      bf16x8 kf = *(const bf16x8*)(
          &kbuf[cur][r * 128 + (((d0 * 2 + hi) ^ (r & 7)) << 4)]);
      sacc = __builtin_amdgcn_mfma_f32_32x32x16_bf16(kf, qf[d0], sacc, 0, 0, 0);
    }
    __builtin_amdgcn_s_setprio(0);

    // p = exp2(s) (Q pre-scaled by log2e), unnormalized; fused pack to bf16
    unsigned pk[8];
#pragma unroll
    for (int m = 0; m < 8; ++m) {
      float e0 = __builtin_amdgcn_exp2f(sacc[2 * m]);
      float e1 = __builtin_amdgcn_exp2f(sacc[2 * m + 1]);
      den += e0 + e1;
      pk[m] = pack2(e0, e1);
    }

    // PV: O^T[dv][q] += V^T · P^T ; P^T B-frags via permlane32_swap
#pragma unroll
    for (int kc = 0; kc < 2; ++kc) {
      const int bs = kc * 4;
      u32x2 r0 = __builtin_amdgcn_permlane32_swap(pk[bs + 0], pk[bs + 2],
                                                  false, false);
      u32x2 r1 = __builtin_amdgcn_permlane32_swap(pk[bs + 1], pk[bs + 3],
                                                  false, false);
      u32x4 pu = {r0.x, r1.x, r0.y, r1.y};
      bf16x8 pf = __builtin_bit_cast(bf16x8, pu);
      __builtin_amdgcn_s_setprio(1);
#pragma unroll
      for (int dvb = 0; dvb < 4; ++dvb) {
        int r = dvb * 32 + l31;
        bf16x8 vf = *(const bf16x8*)(
            &vbuf[cur][r * 64 + (((kc * 2 + hi) ^ (r & 3)) << 4)]);
        oacc[dvb] = __builtin_amdgcn_mfma_f32_32x32x16_bf16(vf, pf,
                                                            oacc[dvb], 0, 0, 0);
      }
      __builtin_amdgcn_s_setprio(0);
    }

    __syncthreads();
    cur ^= 1;
  }

  // write numerator partials (bf16) + denominator (f32)
  unsigned short* OPu = (unsigned short*)(ws + OP_OFF) +
                        (size_t)((batch * 32 + qt) * 8 + split) * 16384;
  int qloc = wid * 32 + l31;
#pragma unroll
  for (int dvb = 0; dvb < 4; ++dvb)
#pragma unroll
    for (int reg = 0; reg < 16; ++reg) {
      int dv = dvb * 32 + (reg & 3) + 8 * (reg >> 2) + 4 * hi;
      OPu[dv * 128 + qloc] = f2bf(oacc[dvb][reg]);
    }
  float dtot = den + __shfl_xor(den, 32, 64);
  if (hi == 0) {
    float* DEN = (float*)(ws + DEN_OFF) +
                 (size_t)((batch * 32 + qt) * 8 + split) * 128;
    DEN[qloc] = dtot;
  }
}

// --------------------------- kernel 3: combine splits -----------------------
// 1024 blocks; each thread produces 8 consecutive outputs (vectorized loads).
__global__ __launch_bounds__(256) void combine_kernel(const char* __restrict__ ws,
                                                      float* __restrict__ out) {
  int idx8 = (blockIdx.x * 256 + threadIdx.x) * 8;  // 2^21 outputs [n][c][s]
  int n = idx8 >> 19;
  int dv = (idx8 >> 12) & 127;
  int s0 = idx8 & 4095;                 // 8-aligned
  int qt = s0 >> 7, ql = s0 & 127;
  const unsigned short* OPu = (const unsigned short*)(ws + OP_OFF);
  const float* DEN = (const float*)(ws + DEN_OFF);
  size_t pb = (size_t)((n * 32 + qt) * 8);
  float num[8], den[8];
#pragma unroll
  for (int j = 0; j < 8; ++j) { num[j] = 0.f; den[j] = 0.f; }
#pragma unroll
  for (int h = 0; h < 8; ++h) {
    bf16x8 v = *(const bf16x8*)(OPu + (pb + h) * 16384 + (size_t)dv * 128 + ql);
    const float* dp = DEN + (pb + h) * 128 + ql;
    float4 d0 = *(const float4*)dp;
    float4 d1 = *(const float4*)(dp + 4);
#pragma unroll
    for (int j = 0; j < 8; ++j) num[j] += (float)v[j];
    den[0] += d0.x; den[1] += d0.y; den[2] += d0.z; den[3] += d0.w;
    den[4] += d1.x; den[5] += d1.y; den[6] += d1.z; den[7] += d1.w;
  }
  float4 o0 = {num[0] / den[0], num[1] / den[1], num[2] / den[2], num[3] / den[3]};
  float4 o1 = {num[4] / den[4], num[5] / den[5], num[6] / den[6], num[7] / den[7]};
  *(float4*)&out[idx8] = o0;
  *(float4*)&out[idx8 + 4] = o1;
}

// ---------------------------------------------------------------------------
extern "C" void kernel_launch(void* const* d_in, const int* in_sizes, int n_in,
                              void* d_out, int out_size, void* d_ws, size_t ws_size,
                              hipStream_t stream) {
  (void)in_sizes; (void)n_in; (void)out_size; (void)ws_size;
  const float* x  = (const float*)d_in[0];
  const float* w1 = (const float*)d_in[1];
  const float* b1 = (const float*)d_in[2];
  const float* a1 = (const float*)d_in[3];
  const float* w2 = (const float*)d_in[4];
  const float* b2 = (const float*)d_in[5];
  const float* a2 = (const float*)d_in[6];
  const float* wa = (const float*)d_in[7];
  const float* ba = (const float*)d_in[8];
  const float* aa = (const float*)d_in[9];
  char* ws = (char*)d_ws;
  float* out = (float*)d_out;

  wcast_kernel<<<dim3(32), dim3(256), 0, stream>>>(w1, w2, wa, ws);
  conv_kernel<<<dim3(512), dim3(256), 0, stream>>>(x, ws, b1, a1, b2, a2, ba, aa);
  attn_kernel<<<dim3(1024), dim3(256), 0, stream>>>(ws);
  combine_kernel<<<dim3(1024), dim3(256), 0, stream>>>(ws, out);
}

// Round 12
// 64.385 us; speedup vs baseline: 1.3795x; 1.0388x over previous
//
#include <hip/hip_runtime.h>
#include <hip/hip_bf16.h>
#include <stdint.h>

// ---------------------------------------------------------------------------
// MultiScaleAttention: x[4,128,4096] -> 3x conv1x1+PReLU -> attention -> out
//   conv (fused transpose): Q [n][s][64] bf16 (*log2e), K/V in MFMA-fragment-
//   ready GLOBAL layouts (1KB contiguous per wave-fragment -> linear LDS
//   staging, zero bank conflicts). Split-bf16 MFMA for fp32-level accuracy.
//   attn: q=64 per wave (q=256/block), KVBLK=32, 2-buffer LDS; p = exp2(S^T)
//   unnormalized; DEN VIA ONES-MFMA (matrix pipe) instead of 64 VALU adds;
//   num bf16 + den f32 partials over 8 kv-splits; combine divides.
// KF layout: [n][t(32k)][d0(4)][slot(64)]*16B, slot=hi*32+l31 ->
//            K[t*32+l31][d0*16+hi*8 ..+8]
// VF layout: [n][t(32k)][dvb*2+kc(8)][slot(64)]*16B, slot=hi*32+l31 ->
//            V^T[dvb*32+l31][t*32+kc*16+hi*8 ..+8]
// ---------------------------------------------------------------------------

typedef float   f32x16 __attribute__((ext_vector_type(16)));
typedef __bf16  bf16x8 __attribute__((ext_vector_type(8)));
typedef __bf16  bf16x2 __attribute__((ext_vector_type(2)));
typedef unsigned int u32x4 __attribute__((ext_vector_type(4)));
typedef unsigned int u32x2 __attribute__((ext_vector_type(2)));

#define L2E 1.4426950408889634f

// workspace layout (bytes); ws_size ~268MB
#define Q_OFF   (0u)                          // [4][4096][64] bf16 = 2MB
#define KF_OFF  (2u << 20)                    // frag-K, 512KB/batch = 2MB
#define VF_OFF  (4u << 20)                    // frag-V, 1MB/batch = 4MB
#define DEN_OFF (8u << 20)                    // [4][16][8][256] f32 = 512KB
#define WH_OFF  ((8u << 20) + (1u << 19))     // W hi bf16 [256][128] = 64KB
#define WL_OFF  (WH_OFF + (1u << 16))
#define OP_OFF  (9u << 20)                    // num bf16 [4][16][8][128][256] = 33.5MB

__device__ inline unsigned short f2bf(float f) {   // hw v_cvt (RNE)
  __bf16 h = (__bf16)f;
  return __builtin_bit_cast(unsigned short, h);
}
__device__ inline float bf2f(unsigned short h) {
  unsigned u = ((unsigned)h) << 16;
  return __builtin_bit_cast(float, u);
}
__device__ inline unsigned pack2(float a, float b) {   // v_cvt_pk_bf16_f32
  bf16x2 t = { (__bf16)a, (__bf16)b };
  return __builtin_bit_cast(unsigned, t);
}

__device__ inline void gld_lds16(const void* g, void* l) {
  __builtin_amdgcn_global_load_lds(
      (const __attribute__((address_space(1))) unsigned*)g,
      (__attribute__((address_space(3))) unsigned*)l, 16, 0, 0);
}

// --------------------------- kernel 0: cast weights ------------------------
__global__ void wcast_kernel(const float* __restrict__ w1, const float* __restrict__ w2,
                             const float* __restrict__ wa, char* __restrict__ ws) {
  int idx = blockIdx.x * 256 + threadIdx.x;   // 32 blocks
  unsigned short* WH = (unsigned short*)(ws + WH_OFF);
  unsigned short* WL = (unsigned short*)(ws + WL_OFF);
#pragma unroll
  for (int r = 0; r < 4; ++r) {
    int i = r * 8192 + idx;                   // 0..32767
    int oc = i >> 7, c = i & 127;
    float v = oc < 64 ? w1[oc * 128 + c]
            : (oc < 128 ? w2[(oc - 64) * 128 + c] : wa[(oc - 128) * 128 + c]);
    __bf16 h = (__bf16)v;
    WH[i] = __builtin_bit_cast(unsigned short, h);
    WL[i] = f2bf(v - (float)h);
  }
}

// ------- kernel 1: conv1x1 + bias + PReLU -> Q, KF, VF (fused transpose) ----
// 512 blocks = 4n * 128 s-tiles(32). Waves: 0->Q(*L2E), 1->K, 2,3->V.
__global__ __launch_bounds__(256) void conv_kernel(
    const float* __restrict__ x, char* __restrict__ ws,
    const float* __restrict__ b1, const float* __restrict__ a1,
    const float* __restrict__ b2, const float* __restrict__ a2,
    const float* __restrict__ ba, const float* __restrict__ aa) {
  int bid = blockIdx.x;
  int n = bid >> 7, st = bid & 127;           // st == kv tile index t
  int sb = st * 32;
  int tid = threadIdx.x;
  int wid = tid >> 6, lane = tid & 63, l31 = lane & 31, hi = lane >> 5;

  __shared__ float xl[128][36];         // x-tile transpose; later reused as vl
  __shared__ float tl[2][64][33];       // Q/K f32 transpose buffers
  float* vl = (float*)xl;               // [128][33] V f32, reuse after MFMA

  const float* xb = x + (size_t)n * 128 * 4096;
#pragma unroll
  for (int it = 0; it < 4; ++it) {      // load 128x32 f32 tile
    int flat4 = tid + 256 * it;
    int c = flat4 >> 3, s4 = flat4 & 7;
    float4 v = *(const float4*)(xb + (size_t)c * 4096 + sb + s4 * 4);
    *(float4*)&xl[c][s4 * 4] = v;
  }
  __syncthreads();

  const char* WH = ws + WH_OFF;
  const char* WL = ws + WL_OFF;
  int oc0 = wid * 64;

  f32x16 acc[2];
  acc[0] = 0.f; acc[1] = 0.f;
#pragma unroll
  for (int c0 = 0; c0 < 8; ++c0) {
    __bf16 eh[8], el[8];
#pragma unroll
    for (int j = 0; j < 8; ++j) {
      float v = xl[c0 * 16 + hi * 8 + j][l31];
      __bf16 h = (__bf16)v;
      eh[j] = h;
      el[j] = (__bf16)(v - (float)h);
    }
    bf16x8 xh = {eh[0], eh[1], eh[2], eh[3], eh[4], eh[5], eh[6], eh[7]};
    bf16x8 xlo = {el[0], el[1], el[2], el[3], el[4], el[5], el[6], el[7]};
#pragma unroll
    for (int mb = 0; mb < 2; ++mb) {
      size_t wo = (size_t)(oc0 + mb * 32 + l31) * 256 + c0 * 32 + hi * 16;
      bf16x8 wh = *(const bf16x8*)(WH + wo);
      bf16x8 wl = *(const bf16x8*)(WL + wo);
      acc[mb] = __builtin_amdgcn_mfma_f32_32x32x16_bf16(wh, xh, acc[mb], 0, 0, 0);
      acc[mb] = __builtin_amdgcn_mfma_f32_32x32x16_bf16(wh, xlo, acc[mb], 0, 0, 0);
      acc[mb] = __builtin_amdgcn_mfma_f32_32x32x16_bf16(wl, xh, acc[mb], 0, 0, 0);
    }
  }
  __syncthreads();                      // all waves done reading xl

  if (wid < 2) {
    const float* bb = wid ? b2 : b1;
    float slope = wid ? a2[0] : a1[0];
    float scl = wid ? 1.0f : L2E;       // fold softmax log2e into Q
#pragma unroll
    for (int mb = 0; mb < 2; ++mb)
#pragma unroll
      for (int reg = 0; reg < 16; ++reg) {
        int row = mb * 32 + (reg & 3) + 8 * (reg >> 2) + 4 * hi;
        float y = acc[mb][reg] + bb[row];
        y = fmaxf(y, 0.f) + slope * fminf(y, 0.f);
        tl[wid][row][l31] = y * scl;
      }
  } else {
    float slope = aa[0];
#pragma unroll
    for (int mb = 0; mb < 2; ++mb)
#pragma unroll
      for (int reg = 0; reg < 16; ++reg) {
        int dv = (wid - 2) * 64 + mb * 32 + (reg & 3) + 8 * (reg >> 2) + 4 * hi;
        float y = acc[mb][reg] + ba[dv];
        y = fmaxf(y, 0.f) + slope * fminf(y, 0.f);
        vl[dv * 33 + l31] = y;
      }
  }
  __syncthreads();

  if (wid == 0) {                       // Q natural [s][64] bf16
    char* Qg = ws + Q_OFF + (size_t)n * (4096 * 128);
#pragma unroll
    for (int it = 0; it < 4; ++it) {
      int sl = (lane >> 3) + it * 8;
      u32x4 pv;
#pragma unroll
      for (int p = 0; p < 4; ++p)
        pv[p] = pack2(tl[0][(lane & 7) * 8 + 2 * p][sl],
                      tl[0][(lane & 7) * 8 + 2 * p + 1][sl]);
      *(u32x4*)(Qg + (size_t)(sb + sl) * 128 + (lane & 7) * 16) = pv;
    }
  } else if (wid == 1) {                // K fragment layout
    char* KFb = ws + KF_OFF + (size_t)n * (512 << 10);
    int d0 = (lane & 7) >> 1, hs = lane & 1;
#pragma unroll
    for (int it = 0; it < 4; ++it) {
      int sl = (lane >> 3) + it * 8;
      u32x4 pv;
#pragma unroll
      for (int p = 0; p < 4; ++p)
        pv[p] = pack2(tl[1][(lane & 7) * 8 + 2 * p][sl],
                      tl[1][(lane & 7) * 8 + 2 * p + 1][sl]);
      *(u32x4*)(KFb + ((size_t)(st * 4 + d0) * 64 + hs * 32 + sl) * 16) = pv;
    }
  }
  // all 256 threads: V fragment stores (512 units of 16B)
  {
    char* VFb = ws + VF_OFF + (size_t)n * (1u << 20);
#pragma unroll
    for (int r = 0; r < 2; ++r) {
      int u = tid + r * 256;
      int dv = u >> 2, sc = u & 3;
      u32x4 pv;
#pragma unroll
      for (int p = 0; p < 4; ++p)
        pv[p] = pack2(vl[dv * 33 + sc * 8 + 2 * p], vl[dv * 33 + sc * 8 + 2 * p + 1]);
      int unit = st * 8 + (dv >> 5) * 2 + (sc >> 1);
      *(u32x4*)(VFb + ((size_t)unit * 64 + (sc & 1) * 32 + (dv & 31)) * 16) = pv;
    }
  }
}

// --------------------------- kernel 2: flash attention ----------------------
// 512 blocks: bid = ((batch*16+qt)<<3)|split -> split==XCD (bid%8).
// Block = 4 waves * 64 q = 256 q; kv = split*512..+512 (16 tiles of 32).
// 2-buffer LDS (24KB); region = stage(t+1) + QK(t) + SM(t) + PV(t) + barrier.
// den accumulated on the MATRIX pipe: dacc = mfma(ones, pf, dacc).
__global__ __launch_bounds__(256, 2) void attn_kernel(char* __restrict__ ws) {
  int bid = blockIdx.x;
  int split = bid & 7;
  int qt = (bid >> 3) & 15;
  int batch = bid >> 7;
  int tid = threadIdx.x;
  int wid = tid >> 6, lane = tid & 63, l31 = lane & 31, hi = lane >> 5;

  const char* Qb  = ws + Q_OFF  + (size_t)batch * (4096 * 128);
  const char* Kt0 = ws + KF_OFF + (size_t)batch * (512 << 10) +
                    (size_t)(split * 16) * 4096;
  const char* Vt0 = ws + VF_OFF + (size_t)batch * (1u << 20) +
                    (size_t)(split * 16) * 8192;

  __shared__ char sbuf[2][12288];       // [0,4K)=K tile, [4K,12K)=V tile

  int q0 = qt * 256 + wid * 64;
  int lo16 = lane * 16;

  bf16x8 qf0[4], qf1[4];                // Q frags for the wave's 2 q-sets
#pragma unroll
  for (int d0 = 0; d0 < 4; ++d0) {
    qf0[d0] = *(const bf16x8*)(Qb + (size_t)(q0 + l31) * 128 + d0 * 32 + hi * 16);
    qf1[d0] = *(const bf16x8*)(Qb + (size_t)(q0 + 32 + l31) * 128 + d0 * 32 + hi * 16);
  }

  const __bf16 one = (__bf16)1.0f;
  const bf16x8 ones = {one, one, one, one, one, one, one, one};

  f32x16 oacc[2][4];
#pragma unroll
  for (int qs = 0; qs < 2; ++qs)
#pragma unroll
    for (int i = 0; i < 4; ++i) oacc[qs][i] = 0.f;
  f32x16 dacc0, dacc1;                  // den accumulators (ones-MFMA)
  dacc0 = 0.f; dacc1 = 0.f;

  // each wave stages 3 of the 12 1KB chunks (K: c<4, V: c>=4)
  auto stage = [&](int b, int t) {
#pragma unroll
    for (int i = 0; i < 3; ++i) {
      int c = wid * 3 + i;
      const char* src = (c < 4) ? Kt0 + (size_t)t * 4096 + c * 1024 + lo16
                                : Vt0 + (size_t)t * 8192 + (c - 4) * 1024 + lo16;
      gld_lds16(src, &sbuf[b][c * 1024]);
    }
  };

  stage(0, 0);
  __syncthreads();                      // compiler drains vmcnt before bar

  for (int t = 0; t < 16; ++t) {
    if (t + 1 < 16) stage((t + 1) & 1, t + 1);   // overlaps this region
    const char* kb = sbuf[t & 1];
    const char* vb = kb + 4096;

    // QK both q-sets: S^T[k][q], k = (reg&3)+8*(reg>>2)+4*hi, q = l31
    f32x16 s0, s1;
    s0 = 0.f; s1 = 0.f;
    __builtin_amdgcn_s_setprio(1);
#pragma unroll
    for (int d0 = 0; d0 < 4; ++d0) {
      bf16x8 kf = *(const bf16x8*)(kb + d0 * 1024 + lo16);
      s0 = __builtin_amdgcn_mfma_f32_32x32x16_bf16(kf, qf0[d0], s0, 0, 0, 0);
      s1 = __builtin_amdgcn_mfma_f32_32x32x16_bf16(kf, qf1[d0], s1, 0, 0, 0);
    }
    __builtin_amdgcn_s_setprio(0);

    // softmax: p = exp2(s) (Q pre-scaled by log2e), unnormalized; pack only
    unsigned pk0[8], pk1[8];
#pragma unroll
    for (int m = 0; m < 8; ++m) {
      float a0 = __builtin_amdgcn_exp2f(s0[2 * m]);
      float a1 = __builtin_amdgcn_exp2f(s0[2 * m + 1]);
      pk0[m] = pack2(a0, a1);
      float b0 = __builtin_amdgcn_exp2f(s1[2 * m]);
      float b1 = __builtin_amdgcn_exp2f(s1[2 * m + 1]);
      pk1[m] = pack2(b0, b1);
    }

    // PV + den: O^T[dv][q] += V^T·P^T ; dacc += ones·P^T (matrix pipe)
#pragma unroll
    for (int kc = 0; kc < 2; ++kc) {
      const int bs = kc * 4;
      u32x2 r0 = __builtin_amdgcn_permlane32_swap(pk0[bs + 0], pk0[bs + 2],
                                                  false, false);
      u32x2 r1 = __builtin_amdgcn_permlane32_swap(pk0[bs + 1], pk0[bs + 3],
                                                  false, false);
      u32x4 pu0 = {r0.x, r1.x, r0.y, r1.y};
      bf16x8 pf0 = __builtin_bit_cast(bf16x8, pu0);
      u32x2 r2 = __builtin_amdgcn_permlane32_swap(pk1[bs + 0], pk1[bs + 2],
                                                  false, false);
      u32x2 r3 = __builtin_amdgcn_permlane32_swap(pk1[bs + 1], pk1[bs + 3],
                                                  false, false);
      u32x4 pu1 = {r2.x, r3.x, r2.y, r3.y};
      bf16x8 pf1 = __builtin_bit_cast(bf16x8, pu1);
      __builtin_amdgcn_s_setprio(1);
      dacc0 = __builtin_amdgcn_mfma_f32_32x32x16_bf16(ones, pf0, dacc0, 0, 0, 0);
      dacc1 = __builtin_amdgcn_mfma_f32_32x32x16_bf16(ones, pf1, dacc1, 0, 0, 0);
#pragma unroll
      for (int dvb = 0; dvb < 4; ++dvb) {
        bf16x8 vf = *(const bf16x8*)(vb + (dvb * 2 + kc) * 1024 + lo16);
        oacc[0][dvb] = __builtin_amdgcn_mfma_f32_32x32x16_bf16(vf, pf0,
                                                               oacc[0][dvb], 0, 0, 0);
        oacc[1][dvb] = __builtin_amdgcn_mfma_f32_32x32x16_bf16(vf, pf1,
                                                               oacc[1][dvb], 0, 0, 0);
      }
      __builtin_amdgcn_s_setprio(0);
    }

    __syncthreads();                    // drains stage(t+1); reads of buf done
  }

  // write numerator partials (bf16, cacheable -> L2/L3 for combine) + den
  unsigned short* OPu = (unsigned short*)(ws + OP_OFF) +
                        (size_t)((batch * 16 + qt) * 8 + split) * 32768;
#pragma unroll
  for (int qs = 0; qs < 2; ++qs) {
    int qloc = wid * 64 + qs * 32 + l31;
#pragma unroll
    for (int dvb = 0; dvb < 4; ++dvb)
#pragma unroll
      for (int reg = 0; reg < 16; ++reg) {
        int dv = dvb * 32 + (reg & 3) + 8 * (reg >> 2) + 4 * hi;
        OPu[dv * 256 + qloc] = f2bf(oacc[qs][dvb][reg]);
      }
    if (hi == 0) {
      // dacc rows are all identical = den[q=l31]; full k-sum (both halves)
      float dtot = qs ? dacc1[0] : dacc0[0];
      float* DEN = (float*)(ws + DEN_OFF) +
                   (size_t)((batch * 16 + qt) * 8 + split) * 256;
      DEN[qloc] = dtot;
    }
  }
}

// --------------------------- kernel 3: combine splits -----------------------
// 1024 blocks; each thread produces 8 consecutive outputs (vectorized loads).
__global__ __launch_bounds__(256) void combine_kernel(const char* __restrict__ ws,
                                                      float* __restrict__ out) {
  int idx8 = (blockIdx.x * 256 + threadIdx.x) * 8;  // 2^21 outputs [n][c][s]
  int n = idx8 >> 19;
  int dv = (idx8 >> 12) & 127;
  int s0 = idx8 & 4095;                 // 8-aligned
  int qt = s0 >> 8, ql = s0 & 255;
  const unsigned short* OPu = (const unsigned short*)(ws + OP_OFF);
  const float* DEN = (const float*)(ws + DEN_OFF);
  size_t pb = (size_t)((n * 16 + qt) * 8);
  float num[8], den[8];
#pragma unroll
  for (int j = 0; j < 8; ++j) { num[j] = 0.f; den[j] = 0.f; }
#pragma unroll
  for (int h = 0; h < 8; ++h) {
    bf16x8 v = *(const bf16x8*)(OPu + (pb + h) * 32768 + (size_t)dv * 256 + ql);
    const float* dp = DEN + (pb + h) * 256 + ql;
    float4 d0 = *(const float4*)dp;
    float4 d1 = *(const float4*)(dp + 4);
#pragma unroll
    for (int j = 0; j < 8; ++j) num[j] += (float)v[j];
    den[0] += d0.x; den[1] += d0.y; den[2] += d0.z; den[3] += d0.w;
    den[4] += d1.x; den[5] += d1.y; den[6] += d1.z; den[7] += d1.w;
  }
  float4 o0 = {num[0] / den[0], num[1] / den[1], num[2] / den[2], num[3] / den[3]};
  float4 o1 = {num[4] / den[4], num[5] / den[5], num[6] / den[6], num[7] / den[7]};
  *(float4*)&out[idx8] = o0;
  *(float4*)&out[idx8 + 4] = o1;
}

// ---------------------------------------------------------------------------
extern "C" void kernel_launch(void* const* d_in, const int* in_sizes, int n_in,
                              void* d_out, int out_size, void* d_ws, size_t ws_size,
                              hipStream_t stream) {
  (void)in_sizes; (void)n_in; (void)out_size; (void)ws_size;
  const float* x  = (const float*)d_in[0];
  const float* w1 = (const float*)d_in[1];
  const float* b1 = (const float*)d_in[2];
  const float* a1 = (const float*)d_in[3];
  const float* w2 = (const float*)d_in[4];
  const float* b2 = (const float*)d_in[5];
  const float* a2 = (const float*)d_in[6];
  const float* wa = (const float*)d_in[7];
  const float* ba = (const float*)d_in[8];
  const float* aa = (const float*)d_in[9];
  char* ws = (char*)d_ws;
  float* out = (float*)d_out;

  wcast_kernel<<<dim3(32), dim3(256), 0, stream>>>(w1, w2, wa, ws);
  conv_kernel<<<dim3(512), dim3(256), 0, stream>>>(x, ws, b1, a1, b2, a2, ba, aa);
  attn_kernel<<<dim3(512), dim3(256), 0, stream>>>(ws);
  combine_kernel<<<dim3(1024), dim3(256), 0, stream>>>(ws, out);
}

// Round 13
// 63.129 us; speedup vs baseline: 1.4069x; 1.0199x over previous
//
#include <hip/hip_runtime.h>
#include <hip/hip_bf16.h>
#include <stdint.h>

// ---------------------------------------------------------------------------
// MultiScaleAttention: x[4,128,4096] -> 3x conv1x1+PReLU -> attention -> out
//   conv (fused transpose): Q [n][s][64] bf16 (*log2e), K/V in MFMA-fragment-
//   ready GLOBAL layouts (1KB contiguous per wave-fragment -> linear LDS
//   staging, zero bank conflicts). Split-bf16 MFMA for fp32-level accuracy.
//   attn: q=64/wave (q=256/block), KVBLK=32, 3-buffer LDS, T4 counted-vmcnt:
//   ONE raw s_barrier per region preceded by s_waitcnt vmcnt(3) -- tile t+1's
//   staging loads stay in flight across the barrier (no drain); vmcnt(0) only
//   at the last tile. p = exp2(S^T) unnormalized; num bf16 + den f32 partials
//   over 8 kv-splits; combine divides.
// KF layout: [n][t(32k)][d0(4)][slot(64)]*16B, slot=hi*32+l31 ->
//            K[t*32+l31][d0*16+hi*8 ..+8]
// VF layout: [n][t(32k)][dvb*2+kc(8)][slot(64)]*16B, slot=hi*32+l31 ->
//            V^T[dvb*32+l31][t*32+kc*16+hi*8 ..+8]
// ---------------------------------------------------------------------------

typedef float   f32x16 __attribute__((ext_vector_type(16)));
typedef __bf16  bf16x8 __attribute__((ext_vector_type(8)));
typedef __bf16  bf16x2 __attribute__((ext_vector_type(2)));
typedef unsigned int u32x4 __attribute__((ext_vector_type(4)));
typedef unsigned int u32x2 __attribute__((ext_vector_type(2)));

#define L2E 1.4426950408889634f

// workspace layout (bytes); ws_size ~268MB
#define Q_OFF   (0u)                          // [4][4096][64] bf16 = 2MB
#define KF_OFF  (2u << 20)                    // frag-K, 512KB/batch = 2MB
#define VF_OFF  (4u << 20)                    // frag-V, 1MB/batch = 4MB
#define DEN_OFF (8u << 20)                    // [4][16][8][256] f32 = 512KB
#define WH_OFF  ((8u << 20) + (1u << 19))     // W hi bf16 [256][128] = 64KB
#define WL_OFF  (WH_OFF + (1u << 16))
#define OP_OFF  (9u << 20)                    // num bf16 [4][16][8][128][256] = 33.5MB

__device__ inline unsigned short f2bf(float f) {   // hw v_cvt (RNE)
  __bf16 h = (__bf16)f;
  return __builtin_bit_cast(unsigned short, h);
}
__device__ inline float bf2f(unsigned short h) {
  unsigned u = ((unsigned)h) << 16;
  return __builtin_bit_cast(float, u);
}
__device__ inline unsigned pack2(float a, float b) {   // v_cvt_pk_bf16_f32
  bf16x2 t = { (__bf16)a, (__bf16)b };
  return __builtin_bit_cast(unsigned, t);
}

__device__ inline void gld_lds16(const void* g, void* l) {
  __builtin_amdgcn_global_load_lds(
      (const __attribute__((address_space(1))) unsigned*)g,
      (__attribute__((address_space(3))) unsigned*)l, 16, 0, 0);
}

// --------------------------- kernel 0: cast weights ------------------------
__global__ void wcast_kernel(const float* __restrict__ w1, const float* __restrict__ w2,
                             const float* __restrict__ wa, char* __restrict__ ws) {
  int idx = blockIdx.x * 256 + threadIdx.x;   // 32 blocks
  unsigned short* WH = (unsigned short*)(ws + WH_OFF);
  unsigned short* WL = (unsigned short*)(ws + WL_OFF);
#pragma unroll
  for (int r = 0; r < 4; ++r) {
    int i = r * 8192 + idx;                   // 0..32767
    int oc = i >> 7, c = i & 127;
    float v = oc < 64 ? w1[oc * 128 + c]
            : (oc < 128 ? w2[(oc - 64) * 128 + c] : wa[(oc - 128) * 128 + c]);
    __bf16 h = (__bf16)v;
    WH[i] = __builtin_bit_cast(unsigned short, h);
    WL[i] = f2bf(v - (float)h);
  }
}

// ------- kernel 1: conv1x1 + bias + PReLU -> Q, KF, VF (fused transpose) ----
// 512 blocks = 4n * 128 s-tiles(32). Waves: 0->Q(*L2E), 1->K, 2,3->V.
__global__ __launch_bounds__(256) void conv_kernel(
    const float* __restrict__ x, char* __restrict__ ws,
    const float* __restrict__ b1, const float* __restrict__ a1,
    const float* __restrict__ b2, const float* __restrict__ a2,
    const float* __restrict__ ba, const float* __restrict__ aa) {
  int bid = blockIdx.x;
  int n = bid >> 7, st = bid & 127;           // st == kv tile index t
  int sb = st * 32;
  int tid = threadIdx.x;
  int wid = tid >> 6, lane = tid & 63, l31 = lane & 31, hi = lane >> 5;

  __shared__ float xl[128][36];         // x-tile transpose; later reused as vl
  __shared__ float tl[2][64][33];       // Q/K f32 transpose buffers
  float* vl = (float*)xl;               // [128][33] V f32, reuse after MFMA

  const float* xb = x + (size_t)n * 128 * 4096;
#pragma unroll
  for (int it = 0; it < 4; ++it) {      // load 128x32 f32 tile
    int flat4 = tid + 256 * it;
    int c = flat4 >> 3, s4 = flat4 & 7;
    float4 v = *(const float4*)(xb + (size_t)c * 4096 + sb + s4 * 4);
    *(float4*)&xl[c][s4 * 4] = v;
  }
  __syncthreads();

  const char* WH = ws + WH_OFF;
  const char* WL = ws + WL_OFF;
  int oc0 = wid * 64;

  f32x16 acc[2];
  acc[0] = 0.f; acc[1] = 0.f;
#pragma unroll
  for (int c0 = 0; c0 < 8; ++c0) {
    __bf16 eh[8], el[8];
#pragma unroll
    for (int j = 0; j < 8; ++j) {
      float v = xl[c0 * 16 + hi * 8 + j][l31];
      __bf16 h = (__bf16)v;
      eh[j] = h;
      el[j] = (__bf16)(v - (float)h);
    }
    bf16x8 xh = {eh[0], eh[1], eh[2], eh[3], eh[4], eh[5], eh[6], eh[7]};
    bf16x8 xlo = {el[0], el[1], el[2], el[3], el[4], el[5], el[6], el[7]};
#pragma unroll
    for (int mb = 0; mb < 2; ++mb) {
      size_t wo = (size_t)(oc0 + mb * 32 + l31) * 256 + c0 * 32 + hi * 16;
      bf16x8 wh = *(const bf16x8*)(WH + wo);
      bf16x8 wl = *(const bf16x8*)(WL + wo);
      acc[mb] = __builtin_amdgcn_mfma_f32_32x32x16_bf16(wh, xh, acc[mb], 0, 0, 0);
      acc[mb] = __builtin_amdgcn_mfma_f32_32x32x16_bf16(wh, xlo, acc[mb], 0, 0, 0);
      acc[mb] = __builtin_amdgcn_mfma_f32_32x32x16_bf16(wl, xh, acc[mb], 0, 0, 0);
    }
  }
  __syncthreads();                      // all waves done reading xl

  if (wid < 2) {
    const float* bb = wid ? b2 : b1;
    float slope = wid ? a2[0] : a1[0];
    float scl = wid ? 1.0f : L2E;       // fold softmax log2e into Q
#pragma unroll
    for (int mb = 0; mb < 2; ++mb)
#pragma unroll
      for (int reg = 0; reg < 16; ++reg) {
        int row = mb * 32 + (reg & 3) + 8 * (reg >> 2) + 4 * hi;
        float y = acc[mb][reg] + bb[row];
        y = fmaxf(y, 0.f) + slope * fminf(y, 0.f);
        tl[wid][row][l31] = y * scl;
      }
  } else {
    float slope = aa[0];
#pragma unroll
    for (int mb = 0; mb < 2; ++mb)
#pragma unroll
      for (int reg = 0; reg < 16; ++reg) {
        int dv = (wid - 2) * 64 + mb * 32 + (reg & 3) + 8 * (reg >> 2) + 4 * hi;
        float y = acc[mb][reg] + ba[dv];
        y = fmaxf(y, 0.f) + slope * fminf(y, 0.f);
        vl[dv * 33 + l31] = y;
      }
  }
  __syncthreads();

  if (wid == 0) {                       // Q natural [s][64] bf16
    char* Qg = ws + Q_OFF + (size_t)n * (4096 * 128);
#pragma unroll
    for (int it = 0; it < 4; ++it) {
      int sl = (lane >> 3) + it * 8;
      u32x4 pv;
#pragma unroll
      for (int p = 0; p < 4; ++p)
        pv[p] = pack2(tl[0][(lane & 7) * 8 + 2 * p][sl],
                      tl[0][(lane & 7) * 8 + 2 * p + 1][sl]);
      *(u32x4*)(Qg + (size_t)(sb + sl) * 128 + (lane & 7) * 16) = pv;
    }
  } else if (wid == 1) {                // K fragment layout
    char* KFb = ws + KF_OFF + (size_t)n * (512 << 10);
    int d0 = (lane & 7) >> 1, hs = lane & 1;
#pragma unroll
    for (int it = 0; it < 4; ++it) {
      int sl = (lane >> 3) + it * 8;
      u32x4 pv;
#pragma unroll
      for (int p = 0; p < 4; ++p)
        pv[p] = pack2(tl[1][(lane & 7) * 8 + 2 * p][sl],
                      tl[1][(lane & 7) * 8 + 2 * p + 1][sl]);
      *(u32x4*)(KFb + ((size_t)(st * 4 + d0) * 64 + hs * 32 + sl) * 16) = pv;
    }
  }
  // all 256 threads: V fragment stores (512 units of 16B)
  {
    char* VFb = ws + VF_OFF + (size_t)n * (1u << 20);
#pragma unroll
    for (int r = 0; r < 2; ++r) {
      int u = tid + r * 256;
      int dv = u >> 2, sc = u & 3;
      u32x4 pv;
#pragma unroll
      for (int p = 0; p < 4; ++p)
        pv[p] = pack2(vl[dv * 33 + sc * 8 + 2 * p], vl[dv * 33 + sc * 8 + 2 * p + 1]);
      int unit = st * 8 + (dv >> 5) * 2 + (sc >> 1);
      *(u32x4*)(VFb + ((size_t)unit * 64 + (sc & 1) * 32 + (dv & 31)) * 16) = pv;
    }
  }
}

// --------------------------- kernel 2: flash attention ----------------------
// 512 blocks: bid = ((batch*16+qt)<<3)|split -> split==XCD (bid%8).
// Block = 4 waves * 64 q = 256 q; kv = split*512..+512 (16 tiles of 32).
// 3-buffer LDS (36KB), stage distance 2; region:
//   {s_waitcnt vmcnt(3); s_barrier; stage(t+2); QK(t)+SM(t)+PV(t)}
// -> tile t+1's staging loads remain in flight across the barrier (T4).
__global__ __launch_bounds__(256, 2) void attn_kernel(char* __restrict__ ws) {
  int bid = blockIdx.x;
  int split = bid & 7;
  int qt = (bid >> 3) & 15;
  int batch = bid >> 7;
  int tid = threadIdx.x;
  int wid = tid >> 6, lane = tid & 63, l31 = lane & 31, hi = lane >> 5;

  const char* Qb  = ws + Q_OFF  + (size_t)batch * (4096 * 128);
  const char* Kt0 = ws + KF_OFF + (size_t)batch * (512 << 10) +
                    (size_t)(split * 16) * 4096;
  const char* Vt0 = ws + VF_OFF + (size_t)batch * (1u << 20) +
                    (size_t)(split * 16) * 8192;

  __shared__ char sbuf[3][12288];       // [0,4K)=K tile, [4K,12K)=V tile

  int q0 = qt * 256 + wid * 64;
  int lo16 = lane * 16;

  bf16x8 qf0[4], qf1[4];                // Q frags for the wave's 2 q-sets
#pragma unroll
  for (int d0 = 0; d0 < 4; ++d0) {
    qf0[d0] = *(const bf16x8*)(Qb + (size_t)(q0 + l31) * 128 + d0 * 32 + hi * 16);
    qf1[d0] = *(const bf16x8*)(Qb + (size_t)(q0 + 32 + l31) * 128 + d0 * 32 + hi * 16);
  }

  f32x16 oacc[2][4];
#pragma unroll
  for (int qs = 0; qs < 2; ++qs)
#pragma unroll
    for (int i = 0; i < 4; ++i) oacc[qs][i] = 0.f;
  float denA0 = 0.f, denA1 = 0.f, denB0 = 0.f, denB1 = 0.f;

  // each wave stages 3 of the 12 1KB chunks (K: c<4, V: c>=4)
  auto stage = [&](int b, int t) {
#pragma unroll
    for (int i = 0; i < 3; ++i) {
      int c = wid * 3 + i;
      const char* src = (c < 4) ? Kt0 + (size_t)t * 4096 + c * 1024 + lo16
                                : Vt0 + (size_t)t * 8192 + (c - 4) * 1024 + lo16;
      gld_lds16(src, &sbuf[b][c * 1024]);
    }
  };

  stage(0, 0);                          // 3 outstanding (this wave)
  stage(1, 1);                          // 6 outstanding

  for (int t = 0; t < 16; ++t) {
    // wait ONLY for tile t's 3 loads (issued 2 regions ago); t+1's in flight
    if (t < 15) asm volatile("s_waitcnt vmcnt(3)" ::: "memory");
    else        asm volatile("s_waitcnt vmcnt(0)" ::: "memory");
    __builtin_amdgcn_s_barrier();       // raw: no drain; all waves' chunks in

    if (t + 2 < 16) stage((t + 2) % 3, t + 2);   // overlaps this region

    const char* kb = sbuf[t % 3];
    const char* vb = kb + 4096;

    // QK both q-sets: S^T[k][q], k = (reg&3)+8*(reg>>2)+4*hi, q = l31
    f32x16 s0, s1;
    s0 = 0.f; s1 = 0.f;
    __builtin_amdgcn_s_setprio(1);
#pragma unroll
    for (int d0 = 0; d0 < 4; ++d0) {
      bf16x8 kf = *(const bf16x8*)(kb + d0 * 1024 + lo16);
      s0 = __builtin_amdgcn_mfma_f32_32x32x16_bf16(kf, qf0[d0], s0, 0, 0, 0);
      s1 = __builtin_amdgcn_mfma_f32_32x32x16_bf16(kf, qf1[d0], s1, 0, 0, 0);
    }
    __builtin_amdgcn_s_setprio(0);

    // softmax: p = exp2(s) (Q pre-scaled by log2e), unnormalized
    unsigned pk0[8], pk1[8];
#pragma unroll
    for (int m = 0; m < 8; ++m) {
      float a0 = __builtin_amdgcn_exp2f(s0[2 * m]);
      float a1 = __builtin_amdgcn_exp2f(s0[2 * m + 1]);
      if (m & 1) denA1 += a0 + a1; else denA0 += a0 + a1;
      pk0[m] = pack2(a0, a1);
      float b0 = __builtin_amdgcn_exp2f(s1[2 * m]);
      float b1 = __builtin_amdgcn_exp2f(s1[2 * m + 1]);
      if (m & 1) denB1 += b0 + b1; else denB0 += b0 + b1;
      pk1[m] = pack2(b0, b1);
    }

    // PV: O^T[dv][q] += V^T · P^T ; each vf read feeds both q-sets
#pragma unroll
    for (int kc = 0; kc < 2; ++kc) {
      const int bs = kc * 4;
      u32x2 r0 = __builtin_amdgcn_permlane32_swap(pk0[bs + 0], pk0[bs + 2],
                                                  false, false);
      u32x2 r1 = __builtin_amdgcn_permlane32_swap(pk0[bs + 1], pk0[bs + 3],
                                                  false, false);
      u32x4 pu0 = {r0.x, r1.x, r0.y, r1.y};
      bf16x8 pf0 = __builtin_bit_cast(bf16x8, pu0);
      u32x2 r2 = __builtin_amdgcn_permlane32_swap(pk1[bs + 0], pk1[bs + 2],
                                                  false, false);
      u32x2 r3 = __builtin_amdgcn_permlane32_swap(pk1[bs + 1], pk1[bs + 3],
                                                  false, false);
      u32x4 pu1 = {r2.x, r3.x, r2.y, r3.y};
      bf16x8 pf1 = __builtin_bit_cast(bf16x8, pu1);
      __builtin_amdgcn_s_setprio(1);
#pragma unroll
      for (int dvb = 0; dvb < 4; ++dvb) {
        bf16x8 vf = *(const bf16x8*)(vb + (dvb * 2 + kc) * 1024 + lo16);
        oacc[0][dvb] = __builtin_amdgcn_mfma_f32_32x32x16_bf16(vf, pf0,
                                                               oacc[0][dvb], 0, 0, 0);
        oacc[1][dvb] = __builtin_amdgcn_mfma_f32_32x32x16_bf16(vf, pf1,
                                                               oacc[1][dvb], 0, 0, 0);
      }
      __builtin_amdgcn_s_setprio(0);
    }
    // no trailing barrier: next region's top barrier provides WAR safety
  }

  // write numerator partials (bf16, cacheable -> L2/L3 for combine) + den
  unsigned short* OPu = (unsigned short*)(ws + OP_OFF) +
                        (size_t)((batch * 16 + qt) * 8 + split) * 32768;
#pragma unroll
  for (int qs = 0; qs < 2; ++qs) {
    int qloc = wid * 64 + qs * 32 + l31;
#pragma unroll
    for (int dvb = 0; dvb < 4; ++dvb)
#pragma unroll
      for (int reg = 0; reg < 16; ++reg) {
        int dv = dvb * 32 + (reg & 3) + 8 * (reg >> 2) + 4 * hi;
        OPu[dv * 256 + qloc] = f2bf(oacc[qs][dvb][reg]);
      }
    float den = qs ? (denB0 + denB1) : (denA0 + denA1);
    float dtot = den + __shfl_xor(den, 32, 64);
    if (hi == 0) {
      float* DEN = (float*)(ws + DEN_OFF) +
                   (size_t)((batch * 16 + qt) * 8 + split) * 256;
      DEN[qloc] = dtot;
    }
  }
}

// --------------------------- kernel 3: combine splits -----------------------
// 1024 blocks; each thread produces 8 consecutive outputs (vectorized loads).
__global__ __launch_bounds__(256) void combine_kernel(const char* __restrict__ ws,
                                                      float* __restrict__ out) {
  int idx8 = (blockIdx.x * 256 + threadIdx.x) * 8;  // 2^21 outputs [n][c][s]
  int n = idx8 >> 19;
  int dv = (idx8 >> 12) & 127;
  int s0 = idx8 & 4095;                 // 8-aligned
  int qt = s0 >> 8, ql = s0 & 255;
  const unsigned short* OPu = (const unsigned short*)(ws + OP_OFF);
  const float* DEN = (const float*)(ws + DEN_OFF);
  size_t pb = (size_t)((n * 16 + qt) * 8);
  float num[8], den[8];
#pragma unroll
  for (int j = 0; j < 8; ++j) { num[j] = 0.f; den[j] = 0.f; }
#pragma unroll
  for (int h = 0; h < 8; ++h) {
    bf16x8 v = *(const bf16x8*)(OPu + (pb + h) * 32768 + (size_t)dv * 256 + ql);
    const float* dp = DEN + (pb + h) * 256 + ql;
    float4 d0 = *(const float4*)dp;
    float4 d1 = *(const float4*)(dp + 4);
#pragma unroll
    for (int j = 0; j < 8; ++j) num[j] += (float)v[j];
    den[0] += d0.x; den[1] += d0.y; den[2] += d0.z; den[3] += d0.w;
    den[4] += d1.x; den[5] += d1.y; den[6] += d1.z; den[7] += d1.w;
  }
  float4 o0 = {num[0] / den[0], num[1] / den[1], num[2] / den[2], num[3] / den[3]};
  float4 o1 = {num[4] / den[4], num[5] / den[5], num[6] / den[6], num[7] / den[7]};
  *(float4*)&out[idx8] = o0;
  *(float4*)&out[idx8 + 4] = o1;
}

// ---------------------------------------------------------------------------
extern "C" void kernel_launch(void* const* d_in, const int* in_sizes, int n_in,
                              void* d_out, int out_size, void* d_ws, size_t ws_size,
                              hipStream_t stream) {
  (void)in_sizes; (void)n_in; (void)out_size; (void)ws_size;
  const float* x  = (const float*)d_in[0];
  const float* w1 = (const float*)d_in[1];
  const float* b1 = (const float*)d_in[2];
  const float* a1 = (const float*)d_in[3];
  const float* w2 = (const float*)d_in[4];
  const float* b2 = (const float*)d_in[5];
  const float* a2 = (const float*)d_in[6];
  const float* wa = (const float*)d_in[7];
  const float* ba = (const float*)d_in[8];
  const float* aa = (const float*)d_in[9];
  char* ws = (char*)d_ws;
  float* out = (float*)d_out;

  wcast_kernel<<<dim3(32), dim3(256), 0, stream>>>(w1, w2, wa, ws);
  conv_kernel<<<dim3(512), dim3(256), 0, stream>>>(x, ws, b1, a1, b2, a2, ba, aa);
  attn_kernel<<<dim3(512), dim3(256), 0, stream>>>(ws);
  combine_kernel<<<dim3(1024), dim3(256), 0, stream>>>(ws, out);
}